// Round 11
// baseline (492.026 us; speedup 1.0000x reference)
//
#include <hip/hip_runtime.h>

typedef _Float16 f16x8 __attribute__((ext_vector_type(8)));
typedef float f32x4 __attribute__((ext_vector_type(4)));

#define MFMA16(a, b, c) __builtin_amdgcn_mfma_f32_16x16x32_f16(a, b, c, 0, 0, 0)

// ---- ws byte offsets (all 16B aligned) ----
#define OFF_W1   0u
#define OFF_W2   524288u
#define OFF_W3   655360u
#define OFF_W4   671744u   // dW1' = (H64 dW1) * w1c/8
#define OFF_W5   688128u
#define OFF_W6   696320u   // pW'  = (H32 pW) * w2c/sqrt(32)
#define OFF_DB1  698368u   // db1' = db1 + w1b*colsum(dW1)
#define OFF_PB   698880u   // pb'  = pb  + w2b*colsum(pW)

__device__ inline void packw(int local, int N, const float* __restrict__ W,
                             _Float16* __restrict__ dst) {
  int j = local & 7;
  int lane = (local >> 3) & 63;
  int fi = local >> 9;
  int NF = N >> 4;
  int nf = fi % NF;
  int kk = fi / NF;
  int k = kk * 32 + ((lane >> 4) << 3) + j;
  int n = (nf << 4) + (lane & 15);
  dst[local] = (_Float16)W[k * N + n];
}

__device__ inline void packh(int local, int N, int K, const float* __restrict__ W,
                             _Float16* __restrict__ dst, float scale) {
  int j = local & 7;
  int lane = (local >> 3) & 63;
  int fi = local >> 9;
  int NF = N >> 4;
  int nf = fi % NF;
  int kk = fi / NF;
  int k = kk * 32 + ((lane >> 4) << 3) + j;
  int n = (nf << 4) + (lane & 15);
  float s = 0.f;
  for (int m = 0; m < K; ++m) {
    float v = W[m * N + n];
    s += (__popc(k & m) & 1) ? -v : v;
  }
  dst[local] = (_Float16)(s * scale);
}

extern "C" __global__ __launch_bounds__(256) void prep_kernel(
    const float* __restrict__ eW1, const float* __restrict__ eW2,
    const float* __restrict__ eW3, const float* __restrict__ dW1,
    const float* __restrict__ dW2, const float* __restrict__ pW,
    const float* __restrict__ w1c, const float* __restrict__ w1b,
    const float* __restrict__ w2c, const float* __restrict__ w2b,
    const float* __restrict__ db1, const float* __restrict__ pb,
    char* __restrict__ ws) {
  int idx = blockIdx.x * 256 + threadIdx.x;
  if (idx < 262144) {
    packw(idx, 512, eW1, (_Float16*)(ws + OFF_W1));
  } else if (idx < 327680) {
    packw(idx - 262144, 128, eW2, (_Float16*)(ws + OFF_W2));
  } else if (idx < 335872) {
    packw(idx - 327680, 64, eW3, (_Float16*)(ws + OFF_W3));
  } else if (idx < 344064) {
    packh(idx - 335872, 128, 64, dW1, (_Float16*)(ws + OFF_W4), w1c[0] * 0.125f);
  } else if (idx < 348160) {
    packw(idx - 344064, 32, dW2, (_Float16*)(ws + OFF_W5));
  } else if (idx < 349184) {
    packh(idx - 348160, 32, 32, pW, (_Float16*)(ws + OFF_W6),
          w2c[0] * 0.17677669529663687f);
  } else if (idx < 349312) {
    int n = idx - 349184;
    float s = 0.f;
    for (int m = 0; m < 64; ++m) s += dW1[m * 128 + n];
    ((float*)(ws + OFF_DB1))[n] = db1[n] + w1b[0] * s;
  } else if (idx < 349344) {
    int n = idx - 349312;
    float s = 0.f;
    for (int m = 0; m < 32; ++m) s += pW[m * 32 + n];
    ((float*)(ws + OFF_PB))[n] = pb[n] + w2b[0] * s;
  }
}

// ---- LDS layout: XOR-swizzled row-major; nu = 16B units per row ----
__device__ inline int hidx(int row, int col, int nu) {
  int u = (col >> 3) ^ ((row & 7) & (nu - 1));
  return row * (nu << 3) + (u << 3) + (col & 7);
}

__device__ inline f16x8 afrag(const _Float16* h, int row, int col, int nu) {
  return *(const f16x8*)(h + hidx(row, col, nu));
}

// Generic epilogue layer; wave computes MT m-tiles at column-tile nf0.
template <int KK, int NUIN, int NUOUT, bool RELU, int MT>
__device__ inline void layerN(const _Float16* hin, _Float16* hout,
                              const f16x8* __restrict__ Wp,
                              const float* __restrict__ bias, int NFtot, int m0,
                              int nf0, int lane, int g, int rr) {
  f32x4 acc[MT];
#pragma unroll
  for (int m = 0; m < MT; ++m) acc[m] = (f32x4){0.f, 0.f, 0.f, 0.f};
#pragma unroll
  for (int kk = 0; kk < KK; ++kk) {
    f16x8 b = Wp[(kk * NFtot + nf0) * 64 + lane];
#pragma unroll
    for (int m = 0; m < MT; ++m) {
      f16x8 a = afrag(hin, (m0 + m) * 16 + rr, kk * 32 + g * 8, NUIN);
      acc[m] = MFMA16(a, b, acc[m]);
    }
  }
  const int n = nf0 * 16 + rr;
  const float bv = bias[n];
#pragma unroll
  for (int m = 0; m < MT; ++m) {
#pragma unroll
    for (int i = 0; i < 4; ++i) {
      float v = acc[m][i] + bv;
      if (RELU) v = fmaxf(v, 0.f);
      hout[hidx((m0 + m) * 16 + g * 4 + i, n, NUOUT)] = (_Float16)v;
    }
  }
}

// ---- x staging (register path, chunk of 128 f32 cols) ----
#define LDCG(P0, P1, C)                                     \
  do {                                                      \
    const float4* p0_ = (P0) + (C) * 32;                    \
    const float4* p1_ = (P1) + (C) * 32;                    \
    q0 = p0_[e];  q1 = p0_[e + 8];  q2 = p0_[e + 16];  q3 = p0_[e + 24]; \
    q4 = p1_[e];  q5 = p1_[e + 8];  q6 = p1_[e + 16];  q7 = p1_[e + 24]; \
  } while (0)

#define DOTR(V) (_Float16)((V).x * d10 + (V).y * d11 + (V).z * d12 + (V).w * d13)
#define DOTZ(V) (_Float16)((V).x * d20 + (V).y * d21 + (V).z * d22 + (V).w * d23)

// write slice elem (ROW, within-chunk col = e + 8*JJ), nu4 swizzle
#define CONVQ2(V, ROW, JJ, SR, SZ)                                \
  do {                                                            \
    int ix_ = (ROW) * 32 + ((((JJ) ^ ((ROW) & 3))) << 3) + e;     \
    (SR)[ix_] = DOTR(V);                                          \
    (SZ)[ix_] = DOTZ(V);                                          \
  } while (0)

#define CONVC(SR, SZ)                                             \
  do {                                                            \
    CONVQ2(q0, r8, 0, SR, SZ); CONVQ2(q1, r8, 1, SR, SZ);         \
    CONVQ2(q2, r8, 2, SR, SZ); CONVQ2(q3, r8, 3, SR, SZ);         \
    CONVQ2(q4, r8 + 64, 0, SR, SZ); CONVQ2(q5, r8 + 64, 1, SR, SZ); \
    CONVQ2(q6, r8 + 64, 2, SR, SZ); CONVQ2(q7, r8 + 64, 3, SR, SZ); \
  } while (0)

// one L1 half-chunk: MFMA 8 m-tiles x 4 nf against slice SL at K-step KK
#define L1HALF(SL, KK)                                                    \
  do {                                                                    \
    f16x8 a0 = afrag((SL), rr, g * 8, 4);                                 \
    f16x8 a1 = afrag((SL), 16 + rr, g * 8, 4);                            \
    f16x8 a2 = afrag((SL), 32 + rr, g * 8, 4);                            \
    f16x8 a3 = afrag((SL), 48 + rr, g * 8, 4);                            \
    f16x8 a4 = afrag((SL), 64 + rr, g * 8, 4);                            \
    f16x8 a5 = afrag((SL), 80 + rr, g * 8, 4);                            \
    f16x8 a6 = afrag((SL), 96 + rr, g * 8, 4);                            \
    f16x8 a7 = afrag((SL), 112 + rr, g * 8, 4);                           \
    _Pragma("unroll") for (int nf = 0; nf < 4; ++nf) {                    \
      f16x8 bb = W1[((KK) * 32 + w * 4 + nf) * 64 + lane];                \
      acc[0][nf] = MFMA16(a0, bb, acc[0][nf]);                            \
      acc[1][nf] = MFMA16(a1, bb, acc[1][nf]);                            \
      acc[2][nf] = MFMA16(a2, bb, acc[2][nf]);                            \
      acc[3][nf] = MFMA16(a3, bb, acc[3][nf]);                            \
      acc[4][nf] = MFMA16(a4, bb, acc[4][nf]);                            \
      acc[5][nf] = MFMA16(a5, bb, acc[5][nf]);                            \
      acc[6][nf] = MFMA16(a6, bb, acc[6][nf]);                            \
      acc[7][nf] = MFMA16(a7, bb, acc[7][nf]);                            \
    }                                                                     \
  } while (0)

// L1 iteration c: prefetch chunk c+2 (if PF), MFMA chunk c from (RDR,RDZ),
// conv chunk c+2 into (WRR,WRZ) — the slot read at iter c-1, freed by its barrier.
#define L1ITER(C, RDR, RDZ, WRR, WRZ, PF)                                 \
  do {                                                                    \
    if (PF) LDCG(xr0, xr1, (C) + 2);                                      \
    L1HALF(RDR, (C));                                                     \
    L1HALF(RDZ, 8 + (C));                                                 \
    if (PF) CONVC(WRR, WRZ);                                              \
    __syncthreads();                                                      \
  } while (0)

// ---- persistent fused kernel: grid 256 (1/CU), NB=2 blocks of 128 rows ----
// LDS 144 KB (147456 B), f16 indices; slice slots A/B/C INSIDE dead h1:
//   h1 [128x512 nu64] @0..65536   (written only AFTER the chunk loop)
//   slots (8192 f16 each = R+Z): A@32768 (R@32768,Z@36864), B@45056 (R,Z@49152),
//   C@53248 (R,Z@57344) — disjoint from epilogue aliases:
//   h2@0 [nu16] 0..16384, h4@16384..32768, h5@40960..45056, h3@65536..73728
// Chunk loop: triple-buffered distance-2; q regs live only within one iteration.
// Epilogue of block b stages block b+1's chunks 0,1 into A,B (HBM stays busy
// during L3..L6; next block's L1 starts hot, no prologue stall).
#define NB 2
#define GRID 256

extern "C" __global__ __launch_bounds__(512)
__attribute__((amdgpu_waves_per_eu(2, 2))) void fused_kernel(
    const float* __restrict__ x, const float* __restrict__ dw1,
    const float* __restrict__ dw2, const float* __restrict__ eb1,
    const float* __restrict__ eb2, const float* __restrict__ eb3,
    const float* __restrict__ db2, const char* __restrict__ ws,
    float* __restrict__ out) {
  __shared__ __align__(16) _Float16 LDS[73728];  // 147456 B
  _Float16* const h1 = LDS;
  _Float16* const h2 = LDS;
  _Float16* const h4 = LDS + 16384;
  _Float16* const h5 = LDS + 40960;
  _Float16* const h3 = LDS + 65536;
  _Float16* const sAR = LDS + 32768;
  _Float16* const sAZ = LDS + 36864;
  _Float16* const sBR = LDS + 45056;
  _Float16* const sBZ = LDS + 49152;
  _Float16* const sCR = LDS + 53248;
  _Float16* const sCZ = LDS + 57344;

  const int tid = threadIdx.x;
  const int wg = blockIdx.x;
  const int lane = tid & 63;
  const int w = tid >> 6;
  const int g = lane >> 4;
  const int rr = lane & 15;
  const int r8 = tid >> 3;
  const int e = tid & 7;

  const float d10 = dw1[0], d11 = dw1[1], d12 = dw1[2], d13 = dw1[3];
  const float d20 = dw2[0], d21 = dw2[1], d22 = dw2[2], d23 = dw2[3];

  const f16x8* __restrict__ W1 = (const f16x8*)(ws + OFF_W1);
  const f16x8* __restrict__ W2 = (const f16x8*)(ws + OFF_W2);
  const f16x8* __restrict__ W3 = (const f16x8*)(ws + OFF_W3);
  const f16x8* __restrict__ W4 = (const f16x8*)(ws + OFF_W4);
  const f16x8* __restrict__ W5 = (const f16x8*)(ws + OFF_W5);
  const f16x8* __restrict__ W6 = (const f16x8*)(ws + OFF_W6);
  const float* __restrict__ db1p = (const float*)(ws + OFF_DB1);
  const float* __restrict__ pbp = (const float*)(ws + OFF_PB);

  float4 q0, q1, q2, q3, q4, q5, q6, q7;

  // ---- prologue: block wg's chunks 0,1 -> A,B ----
  {
    const float4* __restrict__ p0 = (const float4*)x + ((size_t)wg * 128 + r8) * 256;
    const float4* __restrict__ p1 = p0 + (size_t)64 * 256;
    LDCG(p0, p1, 0);
    CONVC(sAR, sAZ);
    LDCG(p0, p1, 1);
    CONVC(sBR, sBZ);
  }
  __syncthreads();

  for (int b = 0; b < NB; ++b) {
    const size_t blkIdx = (size_t)wg + (size_t)GRID * b;
    const float4* __restrict__ xr0 = (const float4*)x + (blkIdx * 128 + r8) * 256;
    const float4* __restrict__ xr1 = xr0 + (size_t)64 * 256;
    const float4* __restrict__ xn0 =
        (const float4*)x + (((size_t)wg + (size_t)GRID * (b + 1)) * 128 + r8) * 256;
    const float4* __restrict__ xn1 = xn0 + (size_t)64 * 256;
    const bool stage = (b + 1 < NB);

    // ---- L1: h1 = relu(h0 @ eW1 + eb1); triple-buffered chunk loop ----
    f32x4 acc[8][4];
#pragma unroll
    for (int m = 0; m < 8; ++m)
#pragma unroll
      for (int n = 0; n < 4; ++n) acc[m][n] = (f32x4){0.f, 0.f, 0.f, 0.f};

    L1ITER(0, sAR, sAZ, sCR, sCZ, 1);
    L1ITER(1, sBR, sBZ, sAR, sAZ, 1);
    L1ITER(2, sCR, sCZ, sBR, sBZ, 1);
    L1ITER(3, sAR, sAZ, sCR, sCZ, 1);
    L1ITER(4, sBR, sBZ, sAR, sAZ, 1);
    L1ITER(5, sCR, sCZ, sBR, sBZ, 1);
    L1ITER(6, sAR, sAZ, sAR, sAZ, 0);
    L1ITER(7, sBR, sBZ, sAR, sAZ, 0);

    // h1 store: wave w owns cols [w*64, w*64+64)  (clobbers slots A/B/C: chunks dead)
#pragma unroll
    for (int mt = 0; mt < 8; ++mt) {
#pragma unroll
      for (int nf = 0; nf < 4; ++nf) {
        const int n = (w * 4 + nf) * 16 + rr;
        const float bv = eb1[n];
#pragma unroll
        for (int i = 0; i < 4; ++i) {
          float v = fmaxf(acc[mt][nf][i] + bv, 0.f);
          h1[hidx(mt * 16 + g * 4 + i, n, 64)] = (_Float16)v;
        }
      }
    }
    __syncthreads();

    // ---- L2 (split): read all of h1, barrier, then write h2@0 ----
    {
      f32x4 acc2[8];
#pragma unroll
      for (int m = 0; m < 8; ++m) acc2[m] = (f32x4){0.f, 0.f, 0.f, 0.f};
#pragma unroll
      for (int kk = 0; kk < 16; ++kk) {
        f16x8 b2 = W2[(kk * 8 + w) * 64 + lane];
#pragma unroll
        for (int m = 0; m < 8; ++m) {
          f16x8 a = afrag(h1, m * 16 + rr, kk * 32 + g * 8, 64);
          acc2[m] = MFMA16(a, b2, acc2[m]);
        }
      }
      const float bv2 = eb2[w * 16 + rr];
      __syncthreads();  // all h1 reads complete before h2 overwrites LDS@0
#pragma unroll
      for (int m = 0; m < 8; ++m) {
#pragma unroll
        for (int i = 0; i < 4; ++i) {
          float v = fmaxf(acc2[m][i] + bv2, 0.f);
          h2[hidx(m * 16 + g * 4 + i, w * 16 + rr, 16)] = (_Float16)v;
        }
      }
    }
    __syncthreads();

    // stage next block's chunk 0: issue loads now (stream under L3/L4)
    if (stage) LDCG(xn0, xn1, 0);

    // L3: h3 = h2 @ eW3 + eb3 (FWHT folded fwd); h2@0 -> h3@65536
    layerN<4, 16, 8, false, 4>(h2, h3, W3, eb3, 4, (w >> 2) * 4, w & 3, lane, g, rr);
    __syncthreads();
    // L4: h4 = relu(h3 @ dW1' + db1'); h3 -> h4@16384
    layerN<2, 8, 16, true, 8>(h3, h4, W4, db1p, 8, 0, w, lane, g, rr);
    __syncthreads();

    if (stage) {
      CONVC(sAR, sAZ);   // chunk 0 -> A (published by L5's barrier)
      LDCG(xn0, xn1, 1); // chunk 1 loads stream under L5/L6
    }

    // L5: h5 = h4 @ dW2 + db2; h4 -> h5@40960
    layerN<4, 16, 4, false, 2>(h4, h5, W5, db2, 2, (w >> 1) * 2, w & 1, lane, g, rr);
    __syncthreads();

    if (stage) CONVC(sBR, sBZ);  // chunk 1 -> B (published by iter0's barrier)

    // L6: out = h5 @ pW' + pb'
    {
      const int m5 = (w >> 1) * 2;
      const int nf5 = w & 1;
      const int n = nf5 * 16 + rr;
      const float bv6 = pbp[n];
      f16x8 b6 = W6[nf5 * 64 + lane];
#pragma unroll
      for (int m = 0; m < 2; ++m) {
        f16x8 a = afrag(h5, (m5 + m) * 16 + rr, g * 8, 4);
        f32x4 o = MFMA16(a, b6, ((f32x4){0.f, 0.f, 0.f, 0.f}));
        const size_t rbase = blkIdx * 128 + (m5 + m) * 16;
#pragma unroll
        for (int i = 0; i < 4; ++i) {
          out[(rbase + g * 4 + i) * 32 + n] = o[i] + bv6;
        }
      }
    }
    // no trailing barrier: next L1 iter0 reads A (conv'd pre-L5-barrier) and
    // writes C (last read at iter 5, many barriers ago); disjoint from h5 reads.
  }
}

extern "C" void kernel_launch(void* const* d_in, const int* in_sizes, int n_in,
                              void* d_out, int out_size, void* d_ws, size_t ws_size,
                              hipStream_t stream) {
  const float* x = (const float*)d_in[0];
  const float* dw1 = (const float*)d_in[1];
  const float* dw2 = (const float*)d_in[2];
  const float* eW1 = (const float*)d_in[3];
  const float* eb1 = (const float*)d_in[4];
  const float* eW2 = (const float*)d_in[5];
  const float* eb2 = (const float*)d_in[6];
  const float* eW3 = (const float*)d_in[7];
  const float* eb3 = (const float*)d_in[8];
  const float* w1c = (const float*)d_in[9];
  const float* w1b = (const float*)d_in[10];
  const float* dW1 = (const float*)d_in[11];
  const float* db1 = (const float*)d_in[12];
  const float* dW2 = (const float*)d_in[13];
  const float* db2 = (const float*)d_in[14];
  const float* w2c = (const float*)d_in[15];
  const float* w2b = (const float*)d_in[16];
  const float* pW = (const float*)d_in[17];
  const float* pb = (const float*)d_in[18];
  char* ws = (char*)d_ws;
  float* out = (float*)d_out;

  prep_kernel<<<dim3(1365), dim3(256), 0, stream>>>(eW1, eW2, eW3, dW1, dW2, pW, w1c, w1b,
                                                    w2c, w2b, db1, pb, ws);
  fused_kernel<<<dim3(GRID), dim3(512), 0, stream>>>(x, dw1, dw2, eb1, eb2, eb3, db2, ws,
                                                     out);
}

// Round 12
// 305.791 us; speedup vs baseline: 1.6090x; 1.6090x over previous
//
#include <hip/hip_runtime.h>

typedef _Float16 f16x8 __attribute__((ext_vector_type(8)));
typedef float f32x4 __attribute__((ext_vector_type(4)));

#define MFMA16(a, b, c) __builtin_amdgcn_mfma_f32_16x16x32_f16(a, b, c, 0, 0, 0)

// ---- ws byte offsets (all 16B aligned) ----
#define OFF_W1   0u
#define OFF_W2   524288u
#define OFF_W3   655360u
#define OFF_W4   671744u   // dW1' = (H64 dW1) * w1c/8
#define OFF_W5   688128u
#define OFF_W6   696320u   // pW'  = (H32 pW) * w2c/sqrt(32)
#define OFF_DB1  698368u   // db1' = db1 + w1b*colsum(dW1)
#define OFF_PB   698880u   // pb'  = pb  + w2b*colsum(pW)

__device__ inline void packw(int local, int N, const float* __restrict__ W,
                             _Float16* __restrict__ dst) {
  int j = local & 7;
  int lane = (local >> 3) & 63;
  int fi = local >> 9;
  int NF = N >> 4;
  int nf = fi % NF;
  int kk = fi / NF;
  int k = kk * 32 + ((lane >> 4) << 3) + j;
  int n = (nf << 4) + (lane & 15);
  dst[local] = (_Float16)W[k * N + n];
}

__device__ inline void packh(int local, int N, int K, const float* __restrict__ W,
                             _Float16* __restrict__ dst, float scale) {
  int j = local & 7;
  int lane = (local >> 3) & 63;
  int fi = local >> 9;
  int NF = N >> 4;
  int nf = fi % NF;
  int kk = fi / NF;
  int k = kk * 32 + ((lane >> 4) << 3) + j;
  int n = (nf << 4) + (lane & 15);
  float s = 0.f;
  for (int m = 0; m < K; ++m) {
    float v = W[m * N + n];
    s += (__popc(k & m) & 1) ? -v : v;
  }
  dst[local] = (_Float16)(s * scale);
}

extern "C" __global__ __launch_bounds__(256) void prep_kernel(
    const float* __restrict__ eW1, const float* __restrict__ eW2,
    const float* __restrict__ eW3, const float* __restrict__ dW1,
    const float* __restrict__ dW2, const float* __restrict__ pW,
    const float* __restrict__ w1c, const float* __restrict__ w1b,
    const float* __restrict__ w2c, const float* __restrict__ w2b,
    const float* __restrict__ db1, const float* __restrict__ pb,
    char* __restrict__ ws) {
  int idx = blockIdx.x * 256 + threadIdx.x;
  if (idx < 262144) {
    packw(idx, 512, eW1, (_Float16*)(ws + OFF_W1));
  } else if (idx < 327680) {
    packw(idx - 262144, 128, eW2, (_Float16*)(ws + OFF_W2));
  } else if (idx < 335872) {
    packw(idx - 327680, 64, eW3, (_Float16*)(ws + OFF_W3));
  } else if (idx < 344064) {
    packh(idx - 335872, 128, 64, dW1, (_Float16*)(ws + OFF_W4), w1c[0] * 0.125f);
  } else if (idx < 348160) {
    packw(idx - 344064, 32, dW2, (_Float16*)(ws + OFF_W5));
  } else if (idx < 349184) {
    packh(idx - 348160, 32, 32, pW, (_Float16*)(ws + OFF_W6),
          w2c[0] * 0.17677669529663687f);
  } else if (idx < 349312) {
    int n = idx - 349184;
    float s = 0.f;
    for (int m = 0; m < 64; ++m) s += dW1[m * 128 + n];
    ((float*)(ws + OFF_DB1))[n] = db1[n] + w1b[0] * s;
  } else if (idx < 349344) {
    int n = idx - 349312;
    float s = 0.f;
    for (int m = 0; m < 32; ++m) s += pW[m * 32 + n];
    ((float*)(ws + OFF_PB))[n] = pb[n] + w2b[0] * s;
  }
}

// ---- LDS layout: XOR-swizzled row-major; nu = 16B units per row ----
__device__ inline int hidx(int row, int col, int nu) {
  int u = (col >> 3) ^ ((row & 7) & (nu - 1));
  return row * (nu << 3) + (u << 3) + (col & 7);
}

__device__ inline f16x8 afrag(const _Float16* h, int row, int col, int nu) {
  return *(const f16x8*)(h + hidx(row, col, nu));
}

// Generic epilogue layer; wave computes MT m-tiles at column-tile nf0.
template <int KK, int NUIN, int NUOUT, bool RELU, int MT>
__device__ inline void layerN(const _Float16* hin, _Float16* hout,
                              const f16x8* __restrict__ Wp,
                              const float* __restrict__ bias, int NFtot, int m0,
                              int nf0, int lane, int g, int rr) {
  f32x4 acc[MT];
#pragma unroll
  for (int m = 0; m < MT; ++m) acc[m] = (f32x4){0.f, 0.f, 0.f, 0.f};
#pragma unroll
  for (int kk = 0; kk < KK; ++kk) {
    f16x8 b = Wp[(kk * NFtot + nf0) * 64 + lane];
#pragma unroll
    for (int m = 0; m < MT; ++m) {
      f16x8 a = afrag(hin, (m0 + m) * 16 + rr, kk * 32 + g * 8, NUIN);
      acc[m] = MFMA16(a, b, acc[m]);
    }
  }
  const int n = nf0 * 16 + rr;
  const float bv = bias[n];
#pragma unroll
  for (int m = 0; m < MT; ++m) {
#pragma unroll
    for (int i = 0; i < 4; ++i) {
      float v = acc[m][i] + bv;
      if (RELU) v = fmaxf(v, 0.f);
      hout[hidx((m0 + m) * 16 + g * 4 + i, n, NUOUT)] = (_Float16)v;
    }
  }
}

// ---- x staging (register path, chunk of 128 f32 cols) ----
// SPILL LAW (R1/R2/R3/R6/R10): q regs must be born and killed with NO MFMA
// phase or barrier inside the live range. Load -> conv -> dead, contiguous.
#define LDCG(P0, P1, C)                                     \
  do {                                                      \
    const float4* p0_ = (P0) + (C) * 32;                    \
    const float4* p1_ = (P1) + (C) * 32;                    \
    q0 = p0_[e];  q1 = p0_[e + 8];  q2 = p0_[e + 16];  q3 = p0_[e + 24]; \
    q4 = p1_[e];  q5 = p1_[e + 8];  q6 = p1_[e + 16];  q7 = p1_[e + 24]; \
  } while (0)

#define DOTR(V) (_Float16)((V).x * d10 + (V).y * d11 + (V).z * d12 + (V).w * d13)
#define DOTZ(V) (_Float16)((V).x * d20 + (V).y * d21 + (V).z * d22 + (V).w * d23)

// write slice elem (ROW, within-chunk col = e + 8*JJ), nu4 swizzle
#define CONVQ2(V, ROW, JJ, SR, SZ)                                \
  do {                                                            \
    int ix_ = (ROW) * 32 + ((((JJ) ^ ((ROW) & 3))) << 3) + e;     \
    (SR)[ix_] = DOTR(V);                                          \
    (SZ)[ix_] = DOTZ(V);                                          \
  } while (0)

#define CONVC(SR, SZ)                                             \
  do {                                                            \
    CONVQ2(q0, r8, 0, SR, SZ); CONVQ2(q1, r8, 1, SR, SZ);         \
    CONVQ2(q2, r8, 2, SR, SZ); CONVQ2(q3, r8, 3, SR, SZ);         \
    CONVQ2(q4, r8 + 64, 0, SR, SZ); CONVQ2(q5, r8 + 64, 1, SR, SZ); \
    CONVQ2(q6, r8 + 64, 2, SR, SZ); CONVQ2(q7, r8 + 64, 3, SR, SZ); \
  } while (0)

// ---- persistent fused kernel: grid 256 (1/CU), NB=2 blocks of 128 rows ----
// LDS 144 KB (147456 B), f16 indices; slices double-buffered INSIDE dead h1:
//   h1 [128x512 nu64] @0..65536   (written only AFTER the chunk loop)
//   s0R@49152 s0Z@53248 s1R@57344 s1Z@61440  (4096 f16 each)
//   epilogue aliases (h1 dead after L2 reads): h2@0 [nu16], h4@16384 [nu16],
//   h5@40960 [nu4], h3@65536 [nu8, 16KB tail]
// Chunk loop = R9's proven one-barrier distance-1 dbuf. Epilogue of block b
// stages block b+1's chunk 0 into s0 CONTIGUOUSLY (load->conv, no barrier in
// q's live range) right after L2's write barrier -> next L1 starts hot, the
// b>=1 prologue disappears. s0/s1 disjoint from all epilogue aliases; staging
// published to next L1 by the L3..L6 barriers.
#define NB 2
#define GRID 256

extern "C" __global__ __launch_bounds__(512)
__attribute__((amdgpu_waves_per_eu(2, 2))) void fused_kernel(
    const float* __restrict__ x, const float* __restrict__ dw1,
    const float* __restrict__ dw2, const float* __restrict__ eb1,
    const float* __restrict__ eb2, const float* __restrict__ eb3,
    const float* __restrict__ db2, const char* __restrict__ ws,
    float* __restrict__ out) {
  __shared__ __align__(16) _Float16 LDS[73728];  // 147456 B
  _Float16* const h1 = LDS;
  _Float16* const h2 = LDS;
  _Float16* const h4 = LDS + 16384;
  _Float16* const h5 = LDS + 40960;
  _Float16* const h3 = LDS + 65536;
  _Float16* const s0R = LDS + 49152;
  _Float16* const s0Z = LDS + 53248;
  _Float16* const s1R = LDS + 57344;
  _Float16* const s1Z = LDS + 61440;

  const int tid = threadIdx.x;
  const int wg = blockIdx.x;
  const int lane = tid & 63;
  const int w = tid >> 6;
  const int g = lane >> 4;
  const int rr = lane & 15;
  const int r8 = tid >> 3;
  const int e = tid & 7;

  const float d10 = dw1[0], d11 = dw1[1], d12 = dw1[2], d13 = dw1[3];
  const float d20 = dw2[0], d21 = dw2[1], d22 = dw2[2], d23 = dw2[3];

  const f16x8* __restrict__ W1 = (const f16x8*)(ws + OFF_W1);
  const f16x8* __restrict__ W2 = (const f16x8*)(ws + OFF_W2);
  const f16x8* __restrict__ W3 = (const f16x8*)(ws + OFF_W3);
  const f16x8* __restrict__ W4 = (const f16x8*)(ws + OFF_W4);
  const f16x8* __restrict__ W5 = (const f16x8*)(ws + OFF_W5);
  const f16x8* __restrict__ W6 = (const f16x8*)(ws + OFF_W6);
  const float* __restrict__ db1p = (const float*)(ws + OFF_DB1);
  const float* __restrict__ pbp = (const float*)(ws + OFF_PB);

  float4 q0, q1, q2, q3, q4, q5, q6, q7;

  // ---- prologue (block 0 only): chunk 0 -> s0 ----
  {
    const float4* __restrict__ p0 = (const float4*)x + ((size_t)wg * 128 + r8) * 256;
    const float4* __restrict__ p1 = p0 + (size_t)64 * 256;
    LDCG(p0, p1, 0);
    CONVC(s0R, s0Z);
  }
  __syncthreads();

  for (int b = 0; b < NB; ++b) {
    const size_t blkIdx = (size_t)wg + (size_t)GRID * b;
    const float4* __restrict__ xrow0 = (const float4*)x + (blkIdx * 128 + r8) * 256;
    const float4* __restrict__ xrow1 = xrow0 + (size_t)64 * 256;
    const bool stage = (b + 1 < NB);

    // ---- L1: h1 = relu(h0 @ eW1 + eb1); 8 chunks; acc[8 mt][4 nf] ----
    f32x4 acc[8][4];
#pragma unroll
    for (int m = 0; m < 8; ++m)
#pragma unroll
      for (int n = 0; n < 4; ++n) acc[m][n] = (f32x4){0.f, 0.f, 0.f, 0.f};

    for (int c = 0; c < 8; ++c) {
      if (c < 7) LDCG(xrow0, xrow1, c + 1);  // in flight across this chunk's MFMA
      const _Float16* sRp = (c & 1) ? s1R : s0R;
      const _Float16* sZp = (c & 1) ? s1Z : s0Z;
#pragma unroll
      for (int S = 0; S < 2; ++S) {
        const _Float16* sl = S ? sZp : sRp;
        const int kk = S ? (8 + c) : c;
        f16x8 a0 = afrag(sl, rr, g * 8, 4);
        f16x8 a1 = afrag(sl, 16 + rr, g * 8, 4);
        f16x8 a2 = afrag(sl, 32 + rr, g * 8, 4);
        f16x8 a3 = afrag(sl, 48 + rr, g * 8, 4);
        f16x8 a4 = afrag(sl, 64 + rr, g * 8, 4);
        f16x8 a5 = afrag(sl, 80 + rr, g * 8, 4);
        f16x8 a6 = afrag(sl, 96 + rr, g * 8, 4);
        f16x8 a7 = afrag(sl, 112 + rr, g * 8, 4);
#pragma unroll
        for (int nf = 0; nf < 4; ++nf) {
          f16x8 bb = W1[(kk * 32 + w * 4 + nf) * 64 + lane];
          acc[0][nf] = MFMA16(a0, bb, acc[0][nf]);
          acc[1][nf] = MFMA16(a1, bb, acc[1][nf]);
          acc[2][nf] = MFMA16(a2, bb, acc[2][nf]);
          acc[3][nf] = MFMA16(a3, bb, acc[3][nf]);
          acc[4][nf] = MFMA16(a4, bb, acc[4][nf]);
          acc[5][nf] = MFMA16(a5, bb, acc[5][nf]);
          acc[6][nf] = MFMA16(a6, bb, acc[6][nf]);
          acc[7][nf] = MFMA16(a7, bb, acc[7][nf]);
        }
      }
      if (c < 7) {  // conv chunk c+1 into the OTHER slice buffer
        _Float16* dR = (c & 1) ? s0R : s1R;
        _Float16* dZ = (c & 1) ? s0Z : s1Z;
        CONVC(dR, dZ);
      }
      __syncthreads();  // publishes conv(c+1), closes MFMA(c) reads
    }

    // h1 store: wave w owns cols [w*64, w*64+64)
#pragma unroll
    for (int mt = 0; mt < 8; ++mt) {
#pragma unroll
      for (int nf = 0; nf < 4; ++nf) {
        const int n = (w * 4 + nf) * 16 + rr;
        const float bv = eb1[n];
#pragma unroll
        for (int i = 0; i < 4; ++i) {
          float v = fmaxf(acc[mt][nf][i] + bv, 0.f);
          h1[hidx(mt * 16 + g * 4 + i, n, 64)] = (_Float16)v;
        }
      }
    }
    __syncthreads();

    // ---- L2 (split): read all of h1, barrier, then write h2@0 ----
    {
      f32x4 acc2[8];
#pragma unroll
      for (int m = 0; m < 8; ++m) acc2[m] = (f32x4){0.f, 0.f, 0.f, 0.f};
#pragma unroll
      for (int kk = 0; kk < 16; ++kk) {
        f16x8 b2 = W2[(kk * 8 + w) * 64 + lane];
#pragma unroll
        for (int m = 0; m < 8; ++m) {
          f16x8 a = afrag(h1, m * 16 + rr, kk * 32 + g * 8, 64);
          acc2[m] = MFMA16(a, b2, acc2[m]);
        }
      }
      const float bv2 = eb2[w * 16 + rr];
      __syncthreads();  // all h1 reads complete before h2 overwrites LDS@0
#pragma unroll
      for (int m = 0; m < 8; ++m) {
#pragma unroll
        for (int i = 0; i < 4; ++i) {
          float v = fmaxf(acc2[m][i] + bv2, 0.f);
          h2[hidx(m * 16 + g * 4 + i, w * 16 + rr, 16)] = (_Float16)v;
        }
      }
    }
    __syncthreads();

    // ---- stage next block's chunk 0 -> s0: CONTIGUOUS load->conv (spill law) ----
    if (stage) {
      const float4* __restrict__ xn0 =
          (const float4*)x + (((size_t)wg + (size_t)GRID * (b + 1)) * 128 + r8) * 256;
      const float4* __restrict__ xn1 = xn0 + (size_t)64 * 256;
      LDCG(xn0, xn1, 0);
      CONVC(s0R, s0Z);  // published to next L1 by the L3..L6 barriers
    }

    // L3: h3 = h2 @ eW3 + eb3 (FWHT folded fwd); h2@0 -> h3@65536
    layerN<4, 16, 8, false, 4>(h2, h3, W3, eb3, 4, (w >> 2) * 4, w & 3, lane, g, rr);
    __syncthreads();
    // L4: h4 = relu(h3 @ dW1' + db1'); h3 -> h4@16384
    layerN<2, 8, 16, true, 8>(h3, h4, W4, db1p, 8, 0, w, lane, g, rr);
    __syncthreads();
    // L5: h5 = h4 @ dW2 + db2; h4 -> h5@40960
    layerN<4, 16, 4, false, 2>(h4, h5, W5, db2, 2, (w >> 1) * 2, w & 1, lane, g, rr);
    __syncthreads();

    // L6: out = h5 @ pW' + pb'
    {
      const int m5 = (w >> 1) * 2;
      const int nf5 = w & 1;
      const int n = nf5 * 16 + rr;
      const float bv6 = pbp[n];
      f16x8 b6 = W6[nf5 * 64 + lane];
#pragma unroll
      for (int m = 0; m < 2; ++m) {
        f16x8 a = afrag(h5, (m5 + m) * 16 + rr, g * 8, 4);
        f32x4 o = MFMA16(a, b6, ((f32x4){0.f, 0.f, 0.f, 0.f}));
        const size_t rbase = blkIdx * 128 + (m5 + m) * 16;
#pragma unroll
        for (int i = 0; i < 4; ++i) {
          out[(rbase + g * 4 + i) * 32 + n] = o[i] + bv6;
        }
      }
    }
    // no trailing barrier: next L1 iter0 reads s0 (staged pre-L3, published by
    // L3..L6 barriers) and writes s1 (disjoint from h5/h3 epilogue regions).
  }
}

extern "C" void kernel_launch(void* const* d_in, const int* in_sizes, int n_in,
                              void* d_out, int out_size, void* d_ws, size_t ws_size,
                              hipStream_t stream) {
  const float* x = (const float*)d_in[0];
  const float* dw1 = (const float*)d_in[1];
  const float* dw2 = (const float*)d_in[2];
  const float* eW1 = (const float*)d_in[3];
  const float* eb1 = (const float*)d_in[4];
  const float* eW2 = (const float*)d_in[5];
  const float* eb2 = (const float*)d_in[6];
  const float* eW3 = (const float*)d_in[7];
  const float* eb3 = (const float*)d_in[8];
  const float* w1c = (const float*)d_in[9];
  const float* w1b = (const float*)d_in[10];
  const float* dW1 = (const float*)d_in[11];
  const float* db1 = (const float*)d_in[12];
  const float* dW2 = (const float*)d_in[13];
  const float* db2 = (const float*)d_in[14];
  const float* w2c = (const float*)d_in[15];
  const float* w2b = (const float*)d_in[16];
  const float* pW = (const float*)d_in[17];
  const float* pb = (const float*)d_in[18];
  char* ws = (char*)d_ws;
  float* out = (float*)d_out;

  prep_kernel<<<dim3(1365), dim3(256), 0, stream>>>(eW1, eW2, eW3, dW1, dW2, pW, w1c, w1b,
                                                    w2c, w2b, db1, pb, ws);
  fused_kernel<<<dim3(GRID), dim3(512), 0, stream>>>(x, dw1, dw2, eb1, eb2, eb3, db2, ws,
                                                     out);
}

// Round 13
// 79.315 us; speedup vs baseline: 6.2035x; 3.8554x over previous
//
#include <hip/hip_runtime.h>

typedef _Float16 f16x8 __attribute__((ext_vector_type(8)));
typedef float f32x4 __attribute__((ext_vector_type(4)));

#define MFMA16(a, b, c) __builtin_amdgcn_mfma_f32_16x16x32_f16(a, b, c, 0, 0, 0)

// ---- ws byte offsets (all 16B aligned) ----
#define OFF_W1   0u
#define OFF_W2   524288u
#define OFF_W3   655360u
#define OFF_W4   671744u   // dW1' = (H64 dW1) * w1c/8
#define OFF_W5   688128u
#define OFF_W6   696320u   // pW'  = (H32 pW) * w2c/sqrt(32)
#define OFF_DB1  698368u   // db1' = db1 + w1b*colsum(dW1)
#define OFF_PB   698880u   // pb'  = pb  + w2b*colsum(pW)

__device__ inline void packw(int local, int N, const float* __restrict__ W,
                             _Float16* __restrict__ dst) {
  int j = local & 7;
  int lane = (local >> 3) & 63;
  int fi = local >> 9;
  int NF = N >> 4;
  int nf = fi % NF;
  int kk = fi / NF;
  int k = kk * 32 + ((lane >> 4) << 3) + j;
  int n = (nf << 4) + (lane & 15);
  dst[local] = (_Float16)W[k * N + n];
}

__device__ inline void packh(int local, int N, int K, const float* __restrict__ W,
                             _Float16* __restrict__ dst, float scale) {
  int j = local & 7;
  int lane = (local >> 3) & 63;
  int fi = local >> 9;
  int NF = N >> 4;
  int nf = fi % NF;
  int kk = fi / NF;
  int k = kk * 32 + ((lane >> 4) << 3) + j;
  int n = (nf << 4) + (lane & 15);
  float s = 0.f;
  for (int m = 0; m < K; ++m) {
    float v = W[m * N + n];
    s += (__popc(k & m) & 1) ? -v : v;
  }
  dst[local] = (_Float16)(s * scale);
}

extern "C" __global__ __launch_bounds__(256) void prep_kernel(
    const float* __restrict__ eW1, const float* __restrict__ eW2,
    const float* __restrict__ eW3, const float* __restrict__ dW1,
    const float* __restrict__ dW2, const float* __restrict__ pW,
    const float* __restrict__ w1c, const float* __restrict__ w1b,
    const float* __restrict__ w2c, const float* __restrict__ w2b,
    const float* __restrict__ db1, const float* __restrict__ pb,
    char* __restrict__ ws) {
  int idx = blockIdx.x * 256 + threadIdx.x;
  if (idx < 262144) {
    packw(idx, 512, eW1, (_Float16*)(ws + OFF_W1));
  } else if (idx < 327680) {
    packw(idx - 262144, 128, eW2, (_Float16*)(ws + OFF_W2));
  } else if (idx < 335872) {
    packw(idx - 327680, 64, eW3, (_Float16*)(ws + OFF_W3));
  } else if (idx < 344064) {
    packh(idx - 335872, 128, 64, dW1, (_Float16*)(ws + OFF_W4), w1c[0] * 0.125f);
  } else if (idx < 348160) {
    packw(idx - 344064, 32, dW2, (_Float16*)(ws + OFF_W5));
  } else if (idx < 349184) {
    packh(idx - 348160, 32, 32, pW, (_Float16*)(ws + OFF_W6),
          w2c[0] * 0.17677669529663687f);
  } else if (idx < 349312) {
    int n = idx - 349184;
    float s = 0.f;
    for (int m = 0; m < 64; ++m) s += dW1[m * 128 + n];
    ((float*)(ws + OFF_DB1))[n] = db1[n] + w1b[0] * s;
  } else if (idx < 349344) {
    int n = idx - 349312;
    float s = 0.f;
    for (int m = 0; m < 32; ++m) s += pW[m * 32 + n];
    ((float*)(ws + OFF_PB))[n] = pb[n] + w2b[0] * s;
  }
}

// ---- LDS layout: XOR-swizzled row-major; nu = 16B units per row ----
__device__ inline int hidx(int row, int col, int nu) {
  int u = (col >> 3) ^ ((row & 7) & (nu - 1));
  return row * (nu << 3) + (u << 3) + (col & 7);
}

__device__ inline f16x8 afrag(const _Float16* h, int row, int col, int nu) {
  return *(const f16x8*)(h + hidx(row, col, nu));
}

// Generic epilogue layer; wave computes MT m-tiles at column-tile nf0.
template <int KK, int NUIN, int NUOUT, bool RELU, int MT>
__device__ inline void layerN(const _Float16* hin, _Float16* hout,
                              const f16x8* __restrict__ Wp,
                              const float* __restrict__ bias, int NFtot, int m0,
                              int nf0, int lane, int g, int rr) {
  f32x4 acc[MT];
#pragma unroll
  for (int m = 0; m < MT; ++m) acc[m] = (f32x4){0.f, 0.f, 0.f, 0.f};
#pragma unroll
  for (int kk = 0; kk < KK; ++kk) {
    f16x8 b = Wp[(kk * NFtot + nf0) * 64 + lane];
#pragma unroll
    for (int m = 0; m < MT; ++m) {
      f16x8 a = afrag(hin, (m0 + m) * 16 + rr, kk * 32 + g * 8, NUIN);
      acc[m] = MFMA16(a, b, acc[m]);
    }
  }
  const int n = nf0 * 16 + rr;
  const float bv = bias[n];
#pragma unroll
  for (int m = 0; m < MT; ++m) {
#pragma unroll
    for (int i = 0; i < 4; ++i) {
      float v = acc[m][i] + bv;
      if (RELU) v = fmaxf(v, 0.f);
      hout[hidx((m0 + m) * 16 + g * 4 + i, n, NUOUT)] = (_Float16)v;
    }
  }
}

// ---- x staging (register path, chunk of 128 f32 cols) ----
// SPILL LAW (R1/R2/R3/R6/R8/R10/R11): q regs must be born and killed within one
// chunk iteration (no MFMA phase or barrier inside the live range), and the
// kernel must be NON-PERSISTENT (any outer block-loop collapses the allocator
// to 128 regs + scratch spill — 3 independent confirmations).
#define LDC(C)                                              \
  do {                                                      \
    const float4* p0_ = xrow0 + (C) * 32;                   \
    const float4* p1_ = xrow1 + (C) * 32;                   \
    q0 = p0_[e];  q1 = p0_[e + 8];  q2 = p0_[e + 16];  q3 = p0_[e + 24]; \
    q4 = p1_[e];  q5 = p1_[e + 8];  q6 = p1_[e + 16];  q7 = p1_[e + 24]; \
  } while (0)

#define DOTR(V) (_Float16)((V).x * d10 + (V).y * d11 + (V).z * d12 + (V).w * d13)
#define DOTZ(V) (_Float16)((V).x * d20 + (V).y * d21 + (V).z * d22 + (V).w * d23)

// write slice elem (ROW, within-chunk col = e + 8*JJ), nu4 swizzle
#define CONVQ2(V, ROW, JJ, SR, SZ)                                \
  do {                                                            \
    int ix_ = (ROW) * 32 + ((((JJ) ^ ((ROW) & 3))) << 3) + e;     \
    (SR)[ix_] = DOTR(V);                                          \
    (SZ)[ix_] = DOTZ(V);                                          \
  } while (0)

#define CONVC(SR, SZ)                                             \
  do {                                                            \
    CONVQ2(q0, r8, 0, SR, SZ); CONVQ2(q1, r8, 1, SR, SZ);         \
    CONVQ2(q2, r8, 2, SR, SZ); CONVQ2(q3, r8, 3, SR, SZ);         \
    CONVQ2(q4, r8 + 64, 0, SR, SZ); CONVQ2(q5, r8 + 64, 1, SR, SZ); \
    CONVQ2(q6, r8 + 64, 2, SR, SZ); CONVQ2(q7, r8 + 64, 3, SR, SZ); \
  } while (0)

// ---- fused kernel: grid 512, one 128-row block per WG, 512 threads ----
// LDS 144 KB (147456 B), f16 indices; slices double-buffered INSIDE dead h1:
//   h1 [128x512 nu64] @0..65536   (written only AFTER the chunk loop)
//   s0R@49152 s0Z@53248 s1R@57344 s1Z@61440  (4096 f16 each; inside h1, dead zone)
//   epilogue aliases (h1 dead after L2 reads): h2@0 [nu16], h4@16384 [nu16],
//   h5@40960 [nu4], h3@65536 [nu8, the 16KB tail]
// Chunk loop: ONE barrier per chunk (dbuf slices): conv(c+1)->s[p^1] while
// MFMA(c) reads s[p]; q regs live only within one iteration (no-spill proven).
// L2 is split read-all / barrier / write (h1<->h2 aliasing race fix).
#define GRID 512

extern "C" __global__ __launch_bounds__(512)
__attribute__((amdgpu_waves_per_eu(2, 2))) void fused_kernel(
    const float* __restrict__ x, const float* __restrict__ dw1,
    const float* __restrict__ dw2, const float* __restrict__ eb1,
    const float* __restrict__ eb2, const float* __restrict__ eb3,
    const float* __restrict__ db2, const char* __restrict__ ws,
    float* __restrict__ out) {
  __shared__ __align__(16) _Float16 LDS[73728];  // 147456 B
  _Float16* const h1 = LDS;
  _Float16* const h2 = LDS;
  _Float16* const h4 = LDS + 16384;
  _Float16* const h5 = LDS + 40960;
  _Float16* const h3 = LDS + 65536;
  _Float16* const s0R = LDS + 49152;
  _Float16* const s0Z = LDS + 53248;
  _Float16* const s1R = LDS + 57344;
  _Float16* const s1Z = LDS + 61440;

  const int tid = threadIdx.x;
  const int wg = blockIdx.x;
  const int lane = tid & 63;
  const int w = tid >> 6;
  const int g = lane >> 4;
  const int rr = lane & 15;
  const int r8 = tid >> 3;
  const int e = tid & 7;

  const float d10 = dw1[0], d11 = dw1[1], d12 = dw1[2], d13 = dw1[3];
  const float d20 = dw2[0], d21 = dw2[1], d22 = dw2[2], d23 = dw2[3];

  const f16x8* __restrict__ W1 = (const f16x8*)(ws + OFF_W1);
  const f16x8* __restrict__ W2 = (const f16x8*)(ws + OFF_W2);
  const f16x8* __restrict__ W3 = (const f16x8*)(ws + OFF_W3);
  const f16x8* __restrict__ W4 = (const f16x8*)(ws + OFF_W4);
  const f16x8* __restrict__ W5 = (const f16x8*)(ws + OFF_W5);
  const f16x8* __restrict__ W6 = (const f16x8*)(ws + OFF_W6);
  const float* __restrict__ db1p = (const float*)(ws + OFF_DB1);
  const float* __restrict__ pbp = (const float*)(ws + OFF_PB);

  const float4* __restrict__ xrow0 =
      (const float4*)x + ((size_t)wg * 128 + r8) * 256;
  const float4* __restrict__ xrow1 = xrow0 + (size_t)64 * 256;

  float4 q0, q1, q2, q3, q4, q5, q6, q7;

  // ---- prologue: chunk 0 -> s0 ----
  LDC(0);
  CONVC(s0R, s0Z);
  __syncthreads();

  // ---- L1: h1 = relu(h0 @ eW1 + eb1); 8 chunks; acc[8 mt][4 nf] ----
  f32x4 acc[8][4];
#pragma unroll
  for (int m = 0; m < 8; ++m)
#pragma unroll
    for (int n = 0; n < 4; ++n) acc[m][n] = (f32x4){0.f, 0.f, 0.f, 0.f};

  for (int c = 0; c < 8; ++c) {
    if (c < 7) LDC(c + 1);  // in flight across this chunk's MFMA
    const _Float16* sRp = (c & 1) ? s1R : s0R;
    const _Float16* sZp = (c & 1) ? s1Z : s0Z;
#pragma unroll
    for (int S = 0; S < 2; ++S) {
      const _Float16* sl = S ? sZp : sRp;
      const int kk = S ? (8 + c) : c;
      f16x8 a0 = afrag(sl, rr, g * 8, 4);
      f16x8 a1 = afrag(sl, 16 + rr, g * 8, 4);
      f16x8 a2 = afrag(sl, 32 + rr, g * 8, 4);
      f16x8 a3 = afrag(sl, 48 + rr, g * 8, 4);
      f16x8 a4 = afrag(sl, 64 + rr, g * 8, 4);
      f16x8 a5 = afrag(sl, 80 + rr, g * 8, 4);
      f16x8 a6 = afrag(sl, 96 + rr, g * 8, 4);
      f16x8 a7 = afrag(sl, 112 + rr, g * 8, 4);
#pragma unroll
      for (int nf = 0; nf < 4; ++nf) {
        f16x8 bb = W1[(kk * 32 + w * 4 + nf) * 64 + lane];
        acc[0][nf] = MFMA16(a0, bb, acc[0][nf]);
        acc[1][nf] = MFMA16(a1, bb, acc[1][nf]);
        acc[2][nf] = MFMA16(a2, bb, acc[2][nf]);
        acc[3][nf] = MFMA16(a3, bb, acc[3][nf]);
        acc[4][nf] = MFMA16(a4, bb, acc[4][nf]);
        acc[5][nf] = MFMA16(a5, bb, acc[5][nf]);
        acc[6][nf] = MFMA16(a6, bb, acc[6][nf]);
        acc[7][nf] = MFMA16(a7, bb, acc[7][nf]);
      }
    }
    if (c < 7) {  // conv chunk c+1 into the OTHER slice buffer (no barrier needed)
      _Float16* dR = (c & 1) ? s0R : s1R;
      _Float16* dZ = (c & 1) ? s0Z : s1Z;
      CONVC(dR, dZ);
    }
    __syncthreads();  // one barrier/chunk: publishes conv(c+1), closes MFMA(c) reads
  }

  // h1 store: wave w owns cols [w*64, w*64+64)
#pragma unroll
  for (int mt = 0; mt < 8; ++mt) {
#pragma unroll
    for (int nf = 0; nf < 4; ++nf) {
      const int n = (w * 4 + nf) * 16 + rr;
      const float bv = eb1[n];
#pragma unroll
      for (int i = 0; i < 4; ++i) {
        float v = fmaxf(acc[mt][nf][i] + bv, 0.f);
        h1[hidx(mt * 16 + g * 4 + i, n, 64)] = (_Float16)v;
      }
    }
  }
  __syncthreads();

  // ---- L2 (race-fixed split): read all of h1, barrier, then write h2@0 ----
  {
    f32x4 acc2[8];
#pragma unroll
    for (int m = 0; m < 8; ++m) acc2[m] = (f32x4){0.f, 0.f, 0.f, 0.f};
#pragma unroll
    for (int kk = 0; kk < 16; ++kk) {
      f16x8 b2 = W2[(kk * 8 + w) * 64 + lane];
#pragma unroll
      for (int m = 0; m < 8; ++m) {
        f16x8 a = afrag(h1, m * 16 + rr, kk * 32 + g * 8, 64);
        acc2[m] = MFMA16(a, b2, acc2[m]);
      }
    }
    const float bv2 = eb2[w * 16 + rr];
    __syncthreads();  // all h1 reads complete before h2 overwrites LDS@0
#pragma unroll
    for (int m = 0; m < 8; ++m) {
#pragma unroll
      for (int i = 0; i < 4; ++i) {
        float v = fmaxf(acc2[m][i] + bv2, 0.f);
        h2[hidx(m * 16 + g * 4 + i, w * 16 + rr, 16)] = (_Float16)v;
      }
    }
  }
  __syncthreads();

  // L3: h3 = h2 @ eW3 + eb3 (FWHT folded fwd); h2@0 -> h3@65536
  layerN<4, 16, 8, false, 4>(h2, h3, W3, eb3, 4, (w >> 2) * 4, w & 3, lane, g, rr);
  __syncthreads();
  // L4: h4 = relu(h3 @ dW1' + db1'); h3 -> h4@16384
  layerN<2, 8, 16, true, 8>(h3, h4, W4, db1p, 8, 0, w, lane, g, rr);
  __syncthreads();
  // L5: h5 = h4 @ dW2 + db2; h4 -> h5@40960
  layerN<4, 16, 4, false, 2>(h4, h5, W5, db2, 2, (w >> 1) * 2, w & 1, lane, g, rr);
  __syncthreads();

  // L6: out = h5 @ pW' + pb'
  {
    const int m5 = (w >> 1) * 2;
    const int nf5 = w & 1;
    const int n = nf5 * 16 + rr;
    const float bv6 = pbp[n];
    f16x8 b6 = W6[nf5 * 64 + lane];
#pragma unroll
    for (int m = 0; m < 2; ++m) {
      f16x8 a = afrag(h5, (m5 + m) * 16 + rr, g * 8, 4);
      f32x4 o = MFMA16(a, b6, ((f32x4){0.f, 0.f, 0.f, 0.f}));
      const size_t rbase = (size_t)wg * 128 + (m5 + m) * 16;
#pragma unroll
      for (int i = 0; i < 4; ++i) {
        out[(rbase + g * 4 + i) * 32 + n] = o[i] + bv6;
      }
    }
  }
}

extern "C" void kernel_launch(void* const* d_in, const int* in_sizes, int n_in,
                              void* d_out, int out_size, void* d_ws, size_t ws_size,
                              hipStream_t stream) {
  const float* x = (const float*)d_in[0];
  const float* dw1 = (const float*)d_in[1];
  const float* dw2 = (const float*)d_in[2];
  const float* eW1 = (const float*)d_in[3];
  const float* eb1 = (const float*)d_in[4];
  const float* eW2 = (const float*)d_in[5];
  const float* eb2 = (const float*)d_in[6];
  const float* eW3 = (const float*)d_in[7];
  const float* eb3 = (const float*)d_in[8];
  const float* w1c = (const float*)d_in[9];
  const float* w1b = (const float*)d_in[10];
  const float* dW1 = (const float*)d_in[11];
  const float* db1 = (const float*)d_in[12];
  const float* dW2 = (const float*)d_in[13];
  const float* db2 = (const float*)d_in[14];
  const float* w2c = (const float*)d_in[15];
  const float* w2b = (const float*)d_in[16];
  const float* pW = (const float*)d_in[17];
  const float* pb = (const float*)d_in[18];
  char* ws = (char*)d_ws;
  float* out = (float*)d_out;

  prep_kernel<<<dim3(1365), dim3(256), 0, stream>>>(eW1, eW2, eW3, dW1, dW2, pW, w1c, w1b,
                                                    w2c, w2b, db1, pb, ws);
  fused_kernel<<<dim3(GRID), dim3(512), 0, stream>>>(x, dw1, dw2, eb1, eb2, eb3, db2, ws,
                                                     out);
}